// Round 9
// baseline (5139.378 us; speedup 1.0000x reference)
//
#include <hip/hip_runtime.h>

typedef unsigned short u16;
typedef unsigned long long u64;
typedef float f32x4 __attribute__((ext_vector_type(4)));
typedef short s16x8 __attribute__((ext_vector_type(8)));

#define B_ 64
#define T_ 512
#define I_ 512
#define H_ 1024
#define NBLK 256
#define NGRP 4      // batch groups (16 batches each), independent barrier domains
#define NMEM 64     // blocks (h-slices) per group
#define NTHR 256

// workspace layout (bytes)
#define OFF_FLG 0                        // u32[4 grp][64 member] PACKED (256B/group) = 1024
#define OFF_SBF 32768                    // s bf16 frags [4 bg][32 kc][64 lane]x16B = 131072
#define OFF_RS  (OFF_SBF + 131072)      // r*s bf16 frags, same layout = 131072
#define OFF_U   (OFF_RS + 131072)       // bf16 U row-major [3][1024][1024] = 6291456
#define OFF_W   (OFF_U + 6291456)       // bf16 W row-major [3][1024][512]  = 3145728

__device__ __forceinline__ u16 f2bf(float f) {
  unsigned u = __float_as_uint(f);
  return (u16)((u + 0x7FFFu + ((u >> 16) & 1u)) >> 16);
}

__device__ __forceinline__ s16x8 pack8(float4 a, float4 b) {
  s16x8 r;
  r[0] = (short)f2bf(a.x); r[1] = (short)f2bf(a.y);
  r[2] = (short)f2bf(a.z); r[3] = (short)f2bf(a.w);
  r[4] = (short)f2bf(b.x); r[5] = (short)f2bf(b.y);
  r[6] = (short)f2bf(b.z); r[7] = (short)f2bf(b.w);
  return r;
}

// 16B device-coherent (MALL-direct) load/store. The load returns BEFORE data
// arrives — caller MUST execute s_waitcnt vmcnt(0) + sched_barrier(0) before use.
__device__ __forceinline__ void ld16_sc1(s16x8* d, const char* p) {
  asm volatile("global_load_dwordx4 %0, %1, off sc0 sc1" : "=v"(*d) : "v"(p));
}
__device__ __forceinline__ void st16_sc1(char* p, s16x8 v) {
  asm volatile("global_store_dwordx4 %0, %1, off sc0 sc1" :: "v"(p), "v"(v) : "memory");
}

__global__ void prep_kernel(const float* __restrict__ s0,
                            const float* __restrict__ Wz, const float* __restrict__ Wr,
                            const float* __restrict__ Ws, const float* __restrict__ Uz,
                            const float* __restrict__ Ur, const float* __restrict__ Us,
                            char* __restrict__ ws) {
  u16* ubf = (u16*)(ws + OFF_U);
  u16* wbf = (u16*)(ws + OFF_W);
  int tid = blockIdx.x * blockDim.x + threadIdx.x;
  int stride = gridDim.x * blockDim.x;
  const int NU = H_ * H_;
  for (int i = tid; i < NU; i += stride) {
    ubf[i] = f2bf(Uz[i]);
    ubf[NU + i] = f2bf(Ur[i]);
    ubf[2 * NU + i] = f2bf(Us[i]);
  }
  const int NW = H_ * I_;
  for (int i = tid; i < NW; i += stride) {
    wbf[i] = f2bf(Wz[i]);
    wbf[NW + i] = f2bf(Wr[i]);
    wbf[2 * NW + i] = f2bf(Ws[i]);
  }
  // s0 -> frag-layout bf16: [bg][kc][lane]; b = bg*16 + (l&15), k = kc*32 + (l>>4)*8
  for (int f = tid; f < 4 * 32 * 64; f += stride) {
    int kc = (f >> 6) & 31, l = f & 63;
    int b = (f >> 11) * 16 + (l & 15);
    int k = kc * 32 + (l >> 4) * 8;
    const float* sp = s0 + (u64)b * H_ + k;
    ushort4 lo, hi;
    lo.x = f2bf(sp[0]); lo.y = f2bf(sp[1]); lo.z = f2bf(sp[2]); lo.w = f2bf(sp[3]);
    hi.x = f2bf(sp[4]); hi.y = f2bf(sp[5]); hi.z = f2bf(sp[6]); hi.w = f2bf(sp[7]);
    ushort4* dst = (ushort4*)(ws + OFF_SBF + (u64)f * 16);
    dst[0] = lo; dst[1] = hi;
  }
}

// all-wave poll of PACKED per-group flags: lane l polls member l's flag.
// No syncthreads needed: flag-order (producer signals only after its epilogue
// reads/stores complete) already serializes LDS buffer reuse across phases.
__device__ __forceinline__ void bar_poll(const unsigned* gf, unsigned bidx, int lane) {
  while (__hip_atomic_load(gf + lane, __ATOMIC_RELAXED, __HIP_MEMORY_SCOPE_AGENT) < bidx)
    __builtin_amdgcn_s_sleep(1);
}

#define SWZ(row, byteInRow, rowShift) \
  (((((row) << (rowShift)) + (byteInRow))) ^ (((row) & 7) << 4))

__global__ __launch_bounds__(NTHR, 1) void scan_kernel(
    const float* __restrict__ x, const float* __restrict__ mask,
    const float* __restrict__ bz, const float* __restrict__ br,
    const float* __restrict__ bs, const float* __restrict__ s0,
    char* __restrict__ ws, float* __restrict__ out) {

  __shared__ u16 u_lds[3 * 16 * 1024];   // 96KB U slices (swizzled, resident)
  __shared__ u16 w_lds[3 * 16 * 512];    // 48KB W slices (swizzled, resident)
  __shared__ f32x4 red[4][2][64];        // 8KB  cross-wave K-split reduction
  __shared__ u16 tbf[16][16];            // 512B wave-0 bf16 transpose tile
  __shared__ float tf32[16][16];         // 1KB  wave-0 f32 transpose tile

  char* fsb = ws + OFF_SBF;
  char* frb = ws + OFF_RS;
  const u16* ubf = (const u16*)(ws + OFF_U);
  const u16* wbf = (const u16*)(ws + OFF_W);
  unsigned* flags = (unsigned*)(ws + OFF_FLG);

  const int tid = threadIdx.x;
  const int jb = blockIdx.x;
  const int bg = jb & 3;          // batch group (16 batches)
  const int hs = jb >> 2;         // h-slice index (16 h columns)
  const int h0 = hs * 16;
  const int lane = tid & 63;
  const int wave = tid >> 6;
  const int ln15 = lane & 15;
  const int kg = lane >> 4;
  const int h = h0 + ln15;
  unsigned* gflag = flags + bg * NMEM;

  // one-time LDS preload of U and W slices for this h-slice
  for (int e = tid * 8; e < 3 * 16 * 1024; e += NTHR * 8) {
    int row = e >> 10, k = e & 1023;
    int g = row >> 4, hi = row & 15;
    uint4 v = *(const uint4*)(ubf + ((u64)(g * H_ + h0 + hi) * H_ + k));
    *(uint4*)((char*)u_lds + SWZ(row, (k << 1), 11)) = v;
  }
  for (int e = tid * 8; e < 3 * 16 * 512; e += NTHR * 8) {
    int row = e >> 9, k = e & 511;
    int g = row >> 4, hi = row & 15;
    uint4 v = *(const uint4*)(wbf + ((u64)(g * H_ + h0 + hi) * I_ + k));
    *(uint4*)((char*)w_lds + SWZ(row, (k << 1), 10)) = v;
  }
  const float bzv = bz[h];
  const float brv = br[h];
  const float bsv = bs[h];
  float sreg[4];   // meaningful in wave 0 only
  #pragma unroll
  for (int j = 0; j < 4; ++j)
    sreg[j] = s0[(u64)(bg * 16 + kg * 4 + j) * H_ + h];
  __syncthreads();

  // per-wave state fragment base (this wave's kc range = wave*8 .. +8)
  const char* sbase = fsb + (((u64)bg * 32 + wave * 8) * 64 + lane) * 16;
  const char* rbase = frb + (((u64)bg * 32 + wave * 8) * 64 + lane) * 16;
  char* sdst = fsb + (((u64)bg * 32 + (hs >> 1)) * 64 + lane + 32 * (hs & 1)) * 16;
  char* rdst = frb + (((u64)bg * 32 + (hs >> 1)) * 64 + lane + 32 * (hs & 1)) * 16;

  // x A-frags for step 0: wave covers x-kc = wave*4 .. +4 (K_x = 512)
  s16x8 xf[4];
  #pragma unroll
  for (int i = 0; i < 4; ++i) {
    const float* xp = x + ((u64)(bg * 16 + ln15) * T_) * I_ + (wave * 4 + i) * 32 + kg * 8;
    xf[i] = pack8(*(const float4*)xp, *(const float4*)(xp + 4));
  }
  unsigned bidx = 0;

  for (int t = 0; t < T_; ++t) {
    float mv[4], zv[4];
    if (wave == 0) {
      #pragma unroll
      for (int j = 0; j < 4; ++j) mv[j] = mask[(u64)(bg * 16 + kg * 4 + j) * T_ + t];
    }

    // ---------------- phase 1: z, r (K = 1024 state + 512 x) ----------------
    s16x8 aS[8];
    #pragma unroll
    for (int q = 0; q < 8; ++q) ld16_sc1(&aS[q], sbase + q * 1024);
    __builtin_amdgcn_sched_barrier(0);
    f32x4 accz = {0.f,0.f,0.f,0.f}, accr = {0.f,0.f,0.f,0.f};
    #pragma unroll
    for (int i = 0; i < 4; ++i) {   // x MFMAs first: independent of sc1 loads
      const int cb = (wave * 4 + i) * 64 + kg * 16;
      s16x8 w0 = *(const s16x8*)((const char*)w_lds + SWZ(ln15, cb, 10));
      s16x8 w1 = *(const s16x8*)((const char*)w_lds + SWZ(16 + ln15, cb, 10));
      accz = __builtin_amdgcn_mfma_f32_16x16x32_bf16(xf[i], w0, accz, 0, 0, 0);
      accr = __builtin_amdgcn_mfma_f32_16x16x32_bf16(xf[i], w1, accr, 0, 0, 0);
    }
    asm volatile("s_waitcnt vmcnt(0)" ::: "memory");
    __builtin_amdgcn_sched_barrier(0);
    #pragma unroll
    for (int q = 0; q < 8; ++q) {
      const int cb = (wave * 8 + q) * 64 + kg * 16;
      s16x8 b0 = *(const s16x8*)((const char*)u_lds + SWZ(ln15, cb, 11));
      s16x8 b1 = *(const s16x8*)((const char*)u_lds + SWZ(16 + ln15, cb, 11));
      accz = __builtin_amdgcn_mfma_f32_16x16x32_bf16(aS[q], b0, accz, 0, 0, 0);
      accr = __builtin_amdgcn_mfma_f32_16x16x32_bf16(aS[q], b1, accr, 0, 0, 0);
    }
    red[wave][0][lane] = accz;
    red[wave][1][lane] = accr;
    __syncthreads();
    ++bidx;
    if (wave == 0) {
      f32x4 az = red[0][0][lane], ar = red[0][1][lane];
      #pragma unroll
      for (int w = 1; w < 4; ++w) { az += red[w][0][lane]; ar += red[w][1][lane]; }
      #pragma unroll
      for (int j = 0; j < 4; ++j) {
        float z = 1.f / (1.f + __expf(-(az[j] + bzv)));
        float r = 1.f / (1.f + __expf(-(ar[j] + brv)));
        zv[j] = z;
        tbf[kg * 4 + j][ln15] = f2bf(sreg[j] * r);
      }
      if (lane < 32) {  // rs tile -> frag layout, MALL-direct store
        s16x8 v = *(const s16x8*)&tbf[lane & 15][(lane >> 4) * 8];
        st16_sc1(rdst, v);
      }
      asm volatile("s_waitcnt vmcnt(0)" ::: "memory");  // drain before flag
      if (lane == 0)
        __hip_atomic_store(gflag + hs, bidx, __ATOMIC_RELAXED, __HIP_MEMORY_SCOPE_AGENT);
    }
    bar_poll(gflag, bidx, lane);

    // ---------------- phase 2: s_hat, state update ----------------
    s16x8 aR[8];
    #pragma unroll
    for (int q = 0; q < 8; ++q) ld16_sc1(&aR[q], rbase + q * 1024);
    __builtin_amdgcn_sched_barrier(0);
    f32x4 accs = {0.f,0.f,0.f,0.f};
    #pragma unroll
    for (int i = 0; i < 4; ++i) {
      const int cb = (wave * 4 + i) * 64 + kg * 16;
      s16x8 w2 = *(const s16x8*)((const char*)w_lds + SWZ(32 + ln15, cb, 10));
      accs = __builtin_amdgcn_mfma_f32_16x16x32_bf16(xf[i], w2, accs, 0, 0, 0);
    }
    asm volatile("s_waitcnt vmcnt(0)" ::: "memory");
    __builtin_amdgcn_sched_barrier(0);
    #pragma unroll
    for (int q = 0; q < 8; ++q) {
      const int cb = (wave * 8 + q) * 64 + kg * 16;
      s16x8 b2 = *(const s16x8*)((const char*)u_lds + SWZ(32 + ln15, cb, 11));
      accs = __builtin_amdgcn_mfma_f32_16x16x32_bf16(aR[q], b2, accs, 0, 0, 0);
    }
    red[wave][0][lane] = accs;
    __syncthreads();
    ++bidx;
    if (wave == 0) {
      f32x4 as_ = red[0][0][lane];
      #pragma unroll
      for (int w = 1; w < 4; ++w) as_ += red[w][0][lane];
      #pragma unroll
      for (int j = 0; j < 4; ++j) {
        float shat = fmaxf(as_[j] + bsv, 0.f);
        float sn = (1.f - zv[j]) * sreg[j] + zv[j] * shat;
        float sf = sreg[j] + mv[j] * (sn - sreg[j]);
        sreg[j] = sf;
        tf32[kg * 4 + j][ln15] = sf;
        tbf[kg * 4 + j][ln15] = f2bf(sf);
      }
      if (lane < 32) {  // new s tile -> frag layout, MALL-direct store
        s16x8 v = *(const s16x8*)&tbf[lane & 15][(lane >> 4) * 8];
        st16_sc1(sdst, v);
      }
      asm volatile("s_waitcnt vmcnt(0)" ::: "memory");
      if (lane == 0)
        __hip_atomic_store(gflag + hs, bidx, __ATOMIC_RELAXED, __HIP_MEMORY_SCOPE_AGENT);
      {  // out store AFTER signal — off the pre-flag drain path
        f32x4 o = *(const f32x4*)&tf32[lane >> 2][(lane & 3) * 4];
        f32x4* op = (f32x4*)(out + ((u64)(bg * 16 + (lane >> 2)) * T_ + t) * H_ + h0 + (lane & 3) * 4);
        __builtin_nontemporal_store(o, op);
      }
    }
    if (t + 1 < T_) {  // next step's x A-frags: overlapped with barrier wait
      #pragma unroll
      for (int i = 0; i < 4; ++i) {
        const float* xp = x + ((u64)(bg * 16 + ln15) * T_ + (t + 1)) * I_ + (wave * 4 + i) * 32 + kg * 8;
        xf[i] = pack8(*(const float4*)xp, *(const float4*)(xp + 4));
      }
    }
    bar_poll(gflag, bidx, lane);
  }
}

extern "C" void kernel_launch(void* const* d_in, const int* in_sizes, int n_in,
                              void* d_out, int out_size, void* d_ws, size_t ws_size,
                              hipStream_t stream) {
  const float* x   = (const float*)d_in[0];
  const float* msk = (const float*)d_in[1];
  const float* s0  = (const float*)d_in[2];
  const float* Ws_ = (const float*)d_in[3];
  const float* Wr_ = (const float*)d_in[4];
  const float* Wz_ = (const float*)d_in[5];
  const float* Us_ = (const float*)d_in[6];
  const float* Ur_ = (const float*)d_in[7];
  const float* Uz_ = (const float*)d_in[8];
  const float* bs_ = (const float*)d_in[9];
  const float* br_ = (const float*)d_in[10];
  const float* bz_ = (const float*)d_in[11];
  float* out = (float*)d_out;
  char* ws = (char*)d_ws;

  (void)hipMemsetAsync(d_ws, 0, 1024, stream);  // packed barrier flags
  hipLaunchKernelGGL(prep_kernel, dim3(1024), dim3(256), 0, stream,
                     s0, Wz_, Wr_, Ws_, Uz_, Ur_, Us_, ws);
  hipLaunchKernelGGL(scan_kernel, dim3(NBLK), dim3(NTHR), 0, stream,
                     x, msk, bz_, br_, bs_, s0, ws, out);
}

// Round 10
// 2649.492 us; speedup vs baseline: 1.9398x; 1.9398x over previous
//
#include <hip/hip_runtime.h>

typedef unsigned short u16;
typedef unsigned long long u64;
typedef float f32x4 __attribute__((ext_vector_type(4)));
typedef short s16x8 __attribute__((ext_vector_type(8)));

#define B_ 64
#define T_ 512
#define I_ 512
#define H_ 1024
#define NBLK 256
#define NGRP 4      // batch groups (16 batches each), independent barrier domains
#define NMEM 64     // blocks (h-slices) per group
#define NTHR 256

// workspace layout (bytes)
#define OFF_FLG 0                        // u32[4 grp][64 member], 128B stride = 32768
#define OFF_SBF 32768                    // s bf16 frags [4 bg][32 kc][64 lane]x16B = 131072
#define OFF_RS  (OFF_SBF + 131072)      // r*s bf16 frags, same layout = 131072
#define OFF_U   (OFF_RS + 131072)       // bf16 U row-major [3][1024][1024] = 6291456
#define OFF_W   (OFF_U + 6291456)       // bf16 W row-major [3][1024][512]  = 3145728

__device__ __forceinline__ u16 f2bf(float f) {
  unsigned u = __float_as_uint(f);
  return (u16)((u + 0x7FFFu + ((u >> 16) & 1u)) >> 16);
}

__device__ __forceinline__ s16x8 pack8(float4 a, float4 b) {
  s16x8 r;
  r[0] = (short)f2bf(a.x); r[1] = (short)f2bf(a.y);
  r[2] = (short)f2bf(a.z); r[3] = (short)f2bf(a.w);
  r[4] = (short)f2bf(b.x); r[5] = (short)f2bf(b.y);
  r[6] = (short)f2bf(b.z); r[7] = (short)f2bf(b.w);
  return r;
}

// 16B device-coherent (MALL-direct) load/store. The load returns BEFORE data
// arrives — caller MUST execute s_waitcnt vmcnt(0) + sched_barrier(0) before use.
__device__ __forceinline__ void ld16_sc1(s16x8* d, const char* p) {
  asm volatile("global_load_dwordx4 %0, %1, off sc0 sc1" : "=v"(*d) : "v"(p));
}
__device__ __forceinline__ void st16_sc1(char* p, s16x8 v) {
  asm volatile("global_store_dwordx4 %0, %1, off sc0 sc1" :: "v"(p), "v"(v) : "memory");
}

__global__ void prep_kernel(const float* __restrict__ s0,
                            const float* __restrict__ Wz, const float* __restrict__ Wr,
                            const float* __restrict__ Ws, const float* __restrict__ Uz,
                            const float* __restrict__ Ur, const float* __restrict__ Us,
                            char* __restrict__ ws) {
  u16* ubf = (u16*)(ws + OFF_U);
  u16* wbf = (u16*)(ws + OFF_W);
  int tid = blockIdx.x * blockDim.x + threadIdx.x;
  int stride = gridDim.x * blockDim.x;
  const int NU = H_ * H_;
  for (int i = tid; i < NU; i += stride) {
    ubf[i] = f2bf(Uz[i]);
    ubf[NU + i] = f2bf(Ur[i]);
    ubf[2 * NU + i] = f2bf(Us[i]);
  }
  const int NW = H_ * I_;
  for (int i = tid; i < NW; i += stride) {
    wbf[i] = f2bf(Wz[i]);
    wbf[NW + i] = f2bf(Wr[i]);
    wbf[2 * NW + i] = f2bf(Ws[i]);
  }
  // s0 -> frag-layout bf16: [bg][kc][lane]; b = bg*16 + (l&15), k = kc*32 + (l>>4)*8
  for (int f = tid; f < 4 * 32 * 64; f += stride) {
    int kc = (f >> 6) & 31, l = f & 63;
    int b = (f >> 11) * 16 + (l & 15);
    int k = kc * 32 + (l >> 4) * 8;
    const float* sp = s0 + (u64)b * H_ + k;
    ushort4 lo, hi;
    lo.x = f2bf(sp[0]); lo.y = f2bf(sp[1]); lo.z = f2bf(sp[2]); lo.w = f2bf(sp[3]);
    hi.x = f2bf(sp[4]); hi.y = f2bf(sp[5]); hi.z = f2bf(sp[6]); hi.w = f2bf(sp[7]);
    ushort4* dst = (ushort4*)(ws + OFF_SBF + (u64)f * 16);
    dst[0] = lo; dst[1] = hi;
  }
}

// R8-proven poll: ONLY wave 0 polls (lane l -> member l's own 128B line),
// then __syncthreads broadcasts the release to the other waves. All-wave /
// packed-line polling floods the MALL and regresses (round-9 lesson).
__device__ __forceinline__ void bar_poll(const unsigned* flags, int bg, unsigned bidx) {
  if (threadIdx.x < NMEM) {
    while (__hip_atomic_load(flags + (u64)(bg * NMEM + threadIdx.x) * 32,
                             __ATOMIC_RELAXED, __HIP_MEMORY_SCOPE_AGENT) < bidx)
      __builtin_amdgcn_s_sleep(1);
  }
  __syncthreads();
}

#define SWZ(row, byteInRow, rowShift) \
  (((((row) << (rowShift)) + (byteInRow))) ^ (((row) & 7) << 4))

__global__ __launch_bounds__(NTHR, 1) void scan_kernel(
    const float* __restrict__ x, const float* __restrict__ mask,
    const float* __restrict__ bz, const float* __restrict__ br,
    const float* __restrict__ bs, const float* __restrict__ s0,
    char* __restrict__ ws, float* __restrict__ out) {

  __shared__ u16 u_lds[3 * 16 * 1024];   // 96KB U slices (swizzled, resident)
  __shared__ u16 w_lds[3 * 16 * 512];    // 48KB W slices (swizzled, resident)
  __shared__ f32x4 red[4][2][64];        // 8KB  cross-wave K-split reduction
  __shared__ u16 tbf[16][16];            // 512B wave-0 bf16 transpose tile
  __shared__ float tf32[16][16];         // 1KB  wave-0 f32 transpose tile

  char* fsb = ws + OFF_SBF;
  char* frb = ws + OFF_RS;
  const u16* ubf = (const u16*)(ws + OFF_U);
  const u16* wbf = (const u16*)(ws + OFF_W);
  unsigned* flags = (unsigned*)(ws + OFF_FLG);

  const int tid = threadIdx.x;
  const int jb = blockIdx.x;
  const int bg = jb & 3;          // batch group (16 batches)
  const int hs = jb >> 2;         // h-slice index (16 h columns)
  const int h0 = hs * 16;
  const int lane = tid & 63;
  const int wave = tid >> 6;
  const int ln15 = lane & 15;
  const int kg = lane >> 4;
  const int h = h0 + ln15;

  // one-time LDS preload of U and W slices for this h-slice
  for (int e = tid * 8; e < 3 * 16 * 1024; e += NTHR * 8) {
    int row = e >> 10, k = e & 1023;
    int g = row >> 4, hi = row & 15;
    uint4 v = *(const uint4*)(ubf + ((u64)(g * H_ + h0 + hi) * H_ + k));
    *(uint4*)((char*)u_lds + SWZ(row, (k << 1), 11)) = v;
  }
  for (int e = tid * 8; e < 3 * 16 * 512; e += NTHR * 8) {
    int row = e >> 9, k = e & 511;
    int g = row >> 4, hi = row & 15;
    uint4 v = *(const uint4*)(wbf + ((u64)(g * H_ + h0 + hi) * I_ + k));
    *(uint4*)((char*)w_lds + SWZ(row, (k << 1), 10)) = v;
  }
  const float bzv = bz[h];
  const float brv = br[h];
  const float bsv = bs[h];
  float sreg[4];   // meaningful in wave 0 only
  #pragma unroll
  for (int j = 0; j < 4; ++j)
    sreg[j] = s0[(u64)(bg * 16 + kg * 4 + j) * H_ + h];
  __syncthreads();

  // per-wave state fragment base (this wave's kc range = wave*8 .. +8)
  const char* sbase = fsb + (((u64)bg * 32 + wave * 8) * 64 + lane) * 16;
  const char* rbase = frb + (((u64)bg * 32 + wave * 8) * 64 + lane) * 16;
  char* sdst = fsb + (((u64)bg * 32 + (hs >> 1)) * 64 + lane + 32 * (hs & 1)) * 16;
  char* rdst = frb + (((u64)bg * 32 + (hs >> 1)) * 64 + lane + 32 * (hs & 1)) * 16;

  // x A-frags + x-projection partial accumulators for step 0, computed
  // OUTSIDE the exchange critical path (recomputed each step in the tail
  // overlap window between signal and poll).
  s16x8 xf[4];
  #pragma unroll
  for (int i = 0; i < 4; ++i) {
    const float* xp = x + ((u64)(bg * 16 + ln15) * T_) * I_ + (wave * 4 + i) * 32 + kg * 8;
    xf[i] = pack8(*(const float4*)xp, *(const float4*)(xp + 4));
  }
  f32x4 axz = {0.f,0.f,0.f,0.f}, axr = {0.f,0.f,0.f,0.f}, axs = {0.f,0.f,0.f,0.f};
  #pragma unroll
  for (int i = 0; i < 4; ++i) {
    const int cb = (wave * 4 + i) * 64 + kg * 16;
    s16x8 w0 = *(const s16x8*)((const char*)w_lds + SWZ(ln15, cb, 10));
    s16x8 w1 = *(const s16x8*)((const char*)w_lds + SWZ(16 + ln15, cb, 10));
    s16x8 w2 = *(const s16x8*)((const char*)w_lds + SWZ(32 + ln15, cb, 10));
    axz = __builtin_amdgcn_mfma_f32_16x16x32_bf16(xf[i], w0, axz, 0, 0, 0);
    axr = __builtin_amdgcn_mfma_f32_16x16x32_bf16(xf[i], w1, axr, 0, 0, 0);
    axs = __builtin_amdgcn_mfma_f32_16x16x32_bf16(xf[i], w2, axs, 0, 0, 0);
  }
  unsigned bidx = 0;

  for (int t = 0; t < T_; ++t) {
    float mv[4], zv[4];
    if (wave == 0) {
      #pragma unroll
      for (int j = 0; j < 4; ++j) mv[j] = mask[(u64)(bg * 16 + kg * 4 + j) * T_ + t];
    }

    // ---------------- phase 1: z, r (state part; x part precomputed) ----------------
    s16x8 aS[8];
    #pragma unroll
    for (int q = 0; q < 8; ++q) ld16_sc1(&aS[q], sbase + q * 1024);
    __builtin_amdgcn_sched_barrier(0);
    asm volatile("s_waitcnt vmcnt(0)" ::: "memory");
    __builtin_amdgcn_sched_barrier(0);
    f32x4 accz = axz, accr = axr;
    #pragma unroll
    for (int q = 0; q < 8; ++q) {
      const int cb = (wave * 8 + q) * 64 + kg * 16;
      s16x8 b0 = *(const s16x8*)((const char*)u_lds + SWZ(ln15, cb, 11));
      s16x8 b1 = *(const s16x8*)((const char*)u_lds + SWZ(16 + ln15, cb, 11));
      accz = __builtin_amdgcn_mfma_f32_16x16x32_bf16(aS[q], b0, accz, 0, 0, 0);
      accr = __builtin_amdgcn_mfma_f32_16x16x32_bf16(aS[q], b1, accr, 0, 0, 0);
    }
    red[wave][0][lane] = accz;
    red[wave][1][lane] = accr;
    __syncthreads();
    ++bidx;
    if (wave == 0) {
      f32x4 az = red[0][0][lane], ar = red[0][1][lane];
      #pragma unroll
      for (int w = 1; w < 4; ++w) { az += red[w][0][lane]; ar += red[w][1][lane]; }
      #pragma unroll
      for (int j = 0; j < 4; ++j) {
        float z = 1.f / (1.f + __expf(-(az[j] + bzv)));
        float r = 1.f / (1.f + __expf(-(ar[j] + brv)));
        zv[j] = z;
        tbf[kg * 4 + j][ln15] = f2bf(sreg[j] * r);
      }
      if (lane < 32) {  // rs tile -> frag layout, MALL-direct store
        s16x8 v = *(const s16x8*)&tbf[lane & 15][(lane >> 4) * 8];
        st16_sc1(rdst, v);
      }
      asm volatile("s_waitcnt vmcnt(0)" ::: "memory");  // drain before flag
      if (lane == 0)
        __hip_atomic_store(flags + (u64)(bg * NMEM + hs) * 32, bidx,
                           __ATOMIC_RELAXED, __HIP_MEMORY_SCOPE_AGENT);
    }
    bar_poll(flags, bg, bidx);

    // ---------------- phase 2: s_hat (state part), state update ----------------
    s16x8 aR[8];
    #pragma unroll
    for (int q = 0; q < 8; ++q) ld16_sc1(&aR[q], rbase + q * 1024);
    __builtin_amdgcn_sched_barrier(0);
    asm volatile("s_waitcnt vmcnt(0)" ::: "memory");
    __builtin_amdgcn_sched_barrier(0);
    f32x4 accs = axs;
    #pragma unroll
    for (int q = 0; q < 8; ++q) {
      const int cb = (wave * 8 + q) * 64 + kg * 16;
      s16x8 b2 = *(const s16x8*)((const char*)u_lds + SWZ(32 + ln15, cb, 11));
      accs = __builtin_amdgcn_mfma_f32_16x16x32_bf16(aR[q], b2, accs, 0, 0, 0);
    }
    red[wave][0][lane] = accs;
    __syncthreads();
    ++bidx;
    if (wave == 0) {
      f32x4 as_ = red[0][0][lane];
      #pragma unroll
      for (int w = 1; w < 4; ++w) as_ += red[w][0][lane];
      #pragma unroll
      for (int j = 0; j < 4; ++j) {
        float shat = fmaxf(as_[j] + bsv, 0.f);
        float sn = (1.f - zv[j]) * sreg[j] + zv[j] * shat;
        float sf = sreg[j] + mv[j] * (sn - sreg[j]);
        sreg[j] = sf;
        tf32[kg * 4 + j][ln15] = sf;
        tbf[kg * 4 + j][ln15] = f2bf(sf);
      }
      if (lane < 32) {  // new s tile -> frag layout, MALL-direct store
        s16x8 v = *(const s16x8*)&tbf[lane & 15][(lane >> 4) * 8];
        st16_sc1(sdst, v);
      }
      asm volatile("s_waitcnt vmcnt(0)" ::: "memory");
      if (lane == 0)
        __hip_atomic_store(flags + (u64)(bg * NMEM + hs) * 32, bidx,
                           __ATOMIC_RELAXED, __HIP_MEMORY_SCOPE_AGENT);
      {  // out store AFTER signal — off the pre-flag drain path
        f32x4 o = *(const f32x4*)&tf32[lane >> 2][(lane & 3) * 4];
        f32x4* op = (f32x4*)(out + ((u64)(bg * 16 + (lane >> 2)) * T_ + t) * H_ + h0 + (lane & 3) * 4);
        __builtin_nontemporal_store(o, op);
      }
    }
    // tail overlap window (signal sent, poll not yet): next step's x A-frags
    // AND all 12 x-projection MFMAs — removed from the serial chain.
    if (t + 1 < T_) {
      #pragma unroll
      for (int i = 0; i < 4; ++i) {
        const float* xp = x + ((u64)(bg * 16 + ln15) * T_ + (t + 1)) * I_ + (wave * 4 + i) * 32 + kg * 8;
        xf[i] = pack8(*(const float4*)xp, *(const float4*)(xp + 4));
      }
      axz = f32x4{0.f,0.f,0.f,0.f}; axr = f32x4{0.f,0.f,0.f,0.f}; axs = f32x4{0.f,0.f,0.f,0.f};
      #pragma unroll
      for (int i = 0; i < 4; ++i) {
        const int cb = (wave * 4 + i) * 64 + kg * 16;
        s16x8 w0 = *(const s16x8*)((const char*)w_lds + SWZ(ln15, cb, 10));
        s16x8 w1 = *(const s16x8*)((const char*)w_lds + SWZ(16 + ln15, cb, 10));
        s16x8 w2 = *(const s16x8*)((const char*)w_lds + SWZ(32 + ln15, cb, 10));
        axz = __builtin_amdgcn_mfma_f32_16x16x32_bf16(xf[i], w0, axz, 0, 0, 0);
        axr = __builtin_amdgcn_mfma_f32_16x16x32_bf16(xf[i], w1, axr, 0, 0, 0);
        axs = __builtin_amdgcn_mfma_f32_16x16x32_bf16(xf[i], w2, axs, 0, 0, 0);
      }
    }
    bar_poll(flags, bg, bidx);
  }
}

extern "C" void kernel_launch(void* const* d_in, const int* in_sizes, int n_in,
                              void* d_out, int out_size, void* d_ws, size_t ws_size,
                              hipStream_t stream) {
  const float* x   = (const float*)d_in[0];
  const float* msk = (const float*)d_in[1];
  const float* s0  = (const float*)d_in[2];
  const float* Ws_ = (const float*)d_in[3];
  const float* Wr_ = (const float*)d_in[4];
  const float* Wz_ = (const float*)d_in[5];
  const float* Us_ = (const float*)d_in[6];
  const float* Ur_ = (const float*)d_in[7];
  const float* Uz_ = (const float*)d_in[8];
  const float* bs_ = (const float*)d_in[9];
  const float* br_ = (const float*)d_in[10];
  const float* bz_ = (const float*)d_in[11];
  float* out = (float*)d_out;
  char* ws = (char*)d_ws;

  (void)hipMemsetAsync(d_ws, 0, 32768, stream);  // barrier flags (128B spread)
  hipLaunchKernelGGL(prep_kernel, dim3(1024), dim3(256), 0, stream,
                     s0, Wz_, Wr_, Ws_, Uz_, Ur_, Us_, ws);
  hipLaunchKernelGGL(scan_kernel, dim3(NBLK), dim3(NTHR), 0, stream,
                     x, msk, bz_, br_, bs_, s0, ws, out);
}